// Round 1
// baseline (2626.677 us; speedup 1.0000x reference)
//
#include <hip/hip_runtime.h>
#include <hip/hip_bf16.h>

// CGCNN forward, MI355X. Structure:
//   x = emb[node_fea]  (f32 + f16 copy)
//   3x: z = [x[i1]|x[i2]|ef] @ Wf[l]  (f16 MFMA 32x32x16, fp32 accum, bf cancels in BN)
//       pass A: z + column stats (sum/sumsq); optionally store z as f16
//       pass B: BN -> sigmoid*softplus -> atomicAdd into nodesum
//       node: seg-mean -> BN -> softplus -> new x (f32+f16)
//   crystal seg-mean -> softplus(@Wc+bc) -> @Wo+bo

#define NN 100000
#define NE 1600000
#define NC 2000
#define KPAD 192
#define EPSB 1e-5f

typedef _Float16 f16;
typedef _Float16 half8 __attribute__((ext_vector_type(8)));
typedef float f32x16 __attribute__((ext_vector_type(16)));

__device__ __forceinline__ f32x16 zero16() {
    f32x16 v;
#pragma unroll
    for (int i = 0; i < 16; i++) v[i] = 0.f;
    return v;
}
__device__ __forceinline__ float softplus_f(float x) {
    return fmaxf(x, 0.f) + log1pf(expf(-fabsf(x)));
}
__device__ __forceinline__ float sigmoid_f(float x) {
    return 1.f / (1.f + expf(-x));
}

// ---------- prep ----------
__global__ void k_prep_x(const int* __restrict__ nf, const float* __restrict__ emb,
                         float* __restrict__ xf, f16* __restrict__ x16) {
    for (int idx = blockIdx.x * blockDim.x + threadIdx.x; idx < NN * 64;
         idx += gridDim.x * blockDim.x) {
        int n = idx >> 6, k = idx & 63;
        float v = emb[nf[n] * 64 + k];
        xf[idx] = v;
        x16[idx] = (f16)v;
    }
}

__global__ void k_prep_ef(const float* __restrict__ ef, f16* __restrict__ ef16) {
    for (long idx = blockIdx.x * blockDim.x + threadIdx.x; idx < (long)NE * 64;
         idx += (long)gridDim.x * blockDim.x) {
        long e = idx >> 6;
        int k = (int)(idx & 63);
        float v = (k < 41) ? ef[e * 41 + k] : 0.f;
        ef16[idx] = (f16)v;
    }
}

__global__ void k_cnt(const int* __restrict__ idx1, const int* __restrict__ idx3,
                      float* cnt1, float* cnt3) {
    for (int i = blockIdx.x * blockDim.x + threadIdx.x; i < NE;
         i += gridDim.x * blockDim.x) {
        atomicAdd(&cnt1[idx1[i]], 1.f);
        if (i < NN) atomicAdd(&cnt3[idx3[i]], 1.f);
    }
}

// WT[col][k] = Wf_l[k][col] (f16, k padded 169->192)
__global__ void k_wt(const float* __restrict__ Wf_l, f16* __restrict__ WT) {
    for (int idx = blockIdx.x * blockDim.x + threadIdx.x; idx < 128 * KPAD;
         idx += gridDim.x * blockDim.x) {
        int col = idx / KPAD, k = idx % KPAD;
        float v = (k < 169) ? Wf_l[k * 128 + col] : 0.f;
        WT[idx] = (f16)v;
    }
}

// ---------- edge GEMM core ----------
__device__ __forceinline__ void edge_mfma(const f16* __restrict__ x16,
                                          const f16* __restrict__ ef16,
                                          const half8 bfr[2][12], int i1, int i2,
                                          long e, int kg, f32x16& acc0, f32x16& acc1) {
    acc0 = zero16();
    acc1 = zero16();
#pragma unroll
    for (int s = 0; s < 4; s++) {
        half8 a = *reinterpret_cast<const half8*>(x16 + (long)i1 * 64 + s * 16 + kg * 8);
        acc0 = __builtin_amdgcn_mfma_f32_32x32x16_f16(a, bfr[0][s], acc0, 0, 0, 0);
        acc1 = __builtin_amdgcn_mfma_f32_32x32x16_f16(a, bfr[1][s], acc1, 0, 0, 0);
    }
#pragma unroll
    for (int s = 0; s < 4; s++) {
        half8 a = *reinterpret_cast<const half8*>(x16 + (long)i2 * 64 + s * 16 + kg * 8);
        acc0 = __builtin_amdgcn_mfma_f32_32x32x16_f16(a, bfr[0][4 + s], acc0, 0, 0, 0);
        acc1 = __builtin_amdgcn_mfma_f32_32x32x16_f16(a, bfr[1][4 + s], acc1, 0, 0, 0);
    }
#pragma unroll
    for (int s = 0; s < 4; s++) {
        half8 a = *reinterpret_cast<const half8*>(ef16 + e * 64 + s * 16 + kg * 8);
        acc0 = __builtin_amdgcn_mfma_f32_32x32x16_f16(a, bfr[0][8 + s], acc0, 0, 0, 0);
        acc1 = __builtin_amdgcn_mfma_f32_32x32x16_f16(a, bfr[1][8 + s], acc1, 0, 0, 0);
    }
}

__device__ __forceinline__ void load_bfr(const f16* __restrict__ WT, int ch, int c,
                                         int kg, half8 bfr[2][12]) {
#pragma unroll
    for (int t = 0; t < 2; t++) {
        int col = 32 * ch + 64 * t + c;
        const f16* bp = WT + col * KPAD + kg * 8;
#pragma unroll
        for (int s = 0; s < 12; s++)
            bfr[t][s] = *reinterpret_cast<const half8*>(bp + s * 16);
    }
}

// pass A: compute z, accumulate column sum/sumsq, optionally store z (f16)
template <bool STORE_Z>
__global__ __launch_bounds__(256) void k_edge_a(
    const f16* __restrict__ x16, const f16* __restrict__ ef16,
    const f16* __restrict__ WT, const int* __restrict__ idx1,
    const int* __restrict__ idx2, float* __restrict__ estats,
    f16* __restrict__ zbuf) {
    __shared__ float lst[256];
    int tid = threadIdx.x;
    int lane = tid & 63;
    int w = tid >> 6;
    int h = w >> 1, ch = w & 1;
    int c = lane & 31, kg = lane >> 5;

    half8 bfr[2][12];
    load_bfr(WT, ch, c, kg, bfr);

    lst[tid] = 0.f;
    __syncthreads();

    float s1[2] = {0.f, 0.f}, s2[2] = {0.f, 0.f};
    const int NT = NE / 64;
    for (int tile = blockIdx.x; tile < NT; tile += gridDim.x) {
        int e0 = tile * 64 + h * 32;
        long e = e0 + c;
        int i1 = idx1[e], i2 = idx2[e];
        f32x16 acc0, acc1;
        edge_mfma(x16, ef16, bfr, i1, i2, e, kg, acc0, acc1);
#pragma unroll
        for (int r = 0; r < 16; r++) {
            float v0 = acc0[r], v1 = acc1[r];
            s1[0] += v0; s2[0] += v0 * v0;
            s1[1] += v1; s2[1] += v1 * v1;
            if (STORE_Z) {
                int row = (r & 3) + 8 * (r >> 2) + 4 * kg;
                long ez = e0 + row;
                zbuf[ez * 128 + 32 * ch + c] = (f16)v0;
                zbuf[ez * 128 + 64 + 32 * ch + c] = (f16)v1;
            }
        }
    }
#pragma unroll
    for (int t = 0; t < 2; t++) {
        s1[t] += __shfl_xor(s1[t], 32, 64);
        s2[t] += __shfl_xor(s2[t], 32, 64);
    }
    if (kg == 0) {
#pragma unroll
        for (int t = 0; t < 2; t++) {
            int col = 32 * ch + 64 * t + c;
            atomicAdd(&lst[col], s1[t]);
            atomicAdd(&lst[128 + col], s2[t]);
        }
    }
    __syncthreads();
    atomicAdd(&estats[tid], lst[tid]);
}

// pass B: BN -> msg -> scatter-add nodesum
template <bool READ_Z>
__global__ __launch_bounds__(256) void k_edge_b(
    const f16* __restrict__ x16, const f16* __restrict__ ef16,
    const f16* __restrict__ WT, const int* __restrict__ idx1,
    const int* __restrict__ idx2, const float* __restrict__ estats,
    const f16* __restrict__ zbuf, const float* __restrict__ g1,
    const float* __restrict__ be1, float* __restrict__ nodesum) {
    int tid = threadIdx.x;
    int lane = tid & 63;
    int w = tid >> 6;
    int h = w >> 1, ch = w & 1;
    int c = lane & 31, kg = lane >> 5;

    float aC[2], bC[2];
#pragma unroll
    for (int t = 0; t < 2; t++) {
        int col = 32 * ch + 64 * t + c;
        float mean = estats[col] * (1.f / NE);
        float var = estats[128 + col] * (1.f / NE) - mean * mean;
        float rs = rsqrtf(var + EPSB);
        aC[t] = g1[col] * rs;
        bC[t] = be1[col] - mean * aC[t];
    }

    half8 bfr[2][12];
    if constexpr (!READ_Z) load_bfr(WT, ch, c, kg, bfr);

    const int NT = NE / 64;
    for (int tile = blockIdx.x; tile < NT; tile += gridDim.x) {
        int e0 = tile * 64 + h * 32;
        float z0[16], z1[16];
        if constexpr (READ_Z) {
#pragma unroll
            for (int r = 0; r < 16; r++) {
                int row = (r & 3) + 8 * (r >> 2) + 4 * kg;
                long ez = e0 + row;
                z0[r] = (float)zbuf[ez * 128 + 32 * ch + c];
                z1[r] = (float)zbuf[ez * 128 + 64 + 32 * ch + c];
            }
        } else {
            long e = e0 + c;
            int i1 = idx1[e], i2 = idx2[e];
            f32x16 acc0, acc1;
            edge_mfma(x16, ef16, bfr, i1, i2, e, kg, acc0, acc1);
#pragma unroll
            for (int r = 0; r < 16; r++) { z0[r] = acc0[r]; z1[r] = acc1[r]; }
        }
#pragma unroll
        for (int r = 0; r < 16; r++) {
            int row = (r & 3) + 8 * (r >> 2) + 4 * kg;
            int ez = e0 + row;
            float g = sigmoid_f(z0[r] * aC[0] + bC[0]);
            float sp = softplus_f(z1[r] * aC[1] + bC[1]);
            float m = g * sp;
            int node = idx1[ez];
            atomicAdd(&nodesum[node * 64 + 32 * ch + c], m);
        }
    }
}

// ---------- node update ----------
__global__ __launch_bounds__(256) void k_node_stats(const float* __restrict__ nodesum,
                                                    const float* __restrict__ cnt1,
                                                    float* __restrict__ nstats) {
    __shared__ float lst[128];
    int tid = threadIdx.x;
    if (tid < 128) lst[tid] = 0.f;
    __syncthreads();
    int j = tid & 63;
    float p1 = 0.f, p2 = 0.f;
    for (int idx = blockIdx.x * 256 + tid; idx < NN * 64; idx += gridDim.x * 256) {
        int n = idx >> 6;
        float raw = nodesum[idx] / fmaxf(cnt1[n], 1.f);
        p1 += raw;
        p2 += raw * raw;
    }
    atomicAdd(&lst[j], p1);
    atomicAdd(&lst[64 + j], p2);
    __syncthreads();
    if (tid < 128) atomicAdd(&nstats[tid], lst[tid]);
}

__global__ __launch_bounds__(256) void k_node_apply(
    const float* __restrict__ nodesum, const float* __restrict__ cnt1,
    const float* __restrict__ nstats, const float* __restrict__ g2,
    const float* __restrict__ be2, float* __restrict__ xf, f16* __restrict__ x16) {
    for (int idx = blockIdx.x * blockDim.x + threadIdx.x; idx < NN * 64;
         idx += gridDim.x * blockDim.x) {
        int n = idx >> 6, j = idx & 63;
        float m = nstats[j] * (1.f / NN);
        float var = nstats[64 + j] * (1.f / NN) - m * m;
        float rs = rsqrtf(var + EPSB);
        float a = g2[j] * rs;
        float b = be2[j] - m * a;
        float raw = nodesum[idx] / fmaxf(cnt1[n], 1.f);
        float v = softplus_f(xf[idx] + raw * a + b);
        xf[idx] = v;
        x16[idx] = (f16)v;
    }
}

// ---------- crystal pooling + MLP ----------
__global__ void k_cry(const float* __restrict__ xf, const int* __restrict__ idx3,
                      float* __restrict__ crsum) {
    for (int idx = blockIdx.x * blockDim.x + threadIdx.x; idx < NN * 64;
         idx += gridDim.x * blockDim.x) {
        int n = idx >> 6, j = idx & 63;
        atomicAdd(&crsum[idx3[n] * 64 + j], xf[idx]);
    }
}

__global__ __launch_bounds__(128) void k_out(const float* __restrict__ crsum,
                                             const float* __restrict__ cnt3,
                                             const float* __restrict__ Wc,
                                             const float* __restrict__ bc,
                                             const float* __restrict__ Wo,
                                             const float* __restrict__ bo,
                                             float* __restrict__ out) {
    __shared__ float crym[64];
    __shared__ float red[4];
    int c = blockIdx.x, tid = threadIdx.x;
    if (tid < 64) crym[tid] = crsum[c * 64 + tid] / fmaxf(cnt3[c], 1.f);
    __syncthreads();
    float hv = bc[tid];
#pragma unroll
    for (int k = 0; k < 64; k++) hv += crym[k] * Wc[k * 128 + tid];
    hv = softplus_f(hv);
    float o0 = hv * Wo[tid * 2 + 0];
    float o1 = hv * Wo[tid * 2 + 1];
#pragma unroll
    for (int off = 32; off > 0; off >>= 1) {
        o0 += __shfl_down(o0, off, 64);
        o1 += __shfl_down(o1, off, 64);
    }
    int wv = tid >> 6;
    if ((tid & 63) == 0) { red[wv * 2] = o0; red[wv * 2 + 1] = o1; }
    __syncthreads();
    if (tid == 0) {
        out[c * 2 + 0] = red[0] + red[2] + bo[0];
        out[c * 2 + 1] = red[1] + red[3] + bo[1];
    }
}

// ---------- launch ----------
static inline size_t al256(size_t x) { return (x + 255) & ~(size_t)255; }

extern "C" void kernel_launch(void* const* d_in, const int* in_sizes, int n_in,
                              void* d_out, int out_size, void* d_ws, size_t ws_size,
                              hipStream_t stream) {
    const int* node_fea = (const int*)d_in[0];
    const float* edge_fea = (const float*)d_in[1];
    const int* idx1 = (const int*)d_in[2];
    const int* idx2 = (const int*)d_in[3];
    const int* idx3 = (const int*)d_in[4];
    const float* emb = (const float*)d_in[5];
    const float* Wf = (const float*)d_in[6];
    // d_in[7] = bf: mathematically cancels inside training-mode BN, unused.
    const float* g1 = (const float*)d_in[8];
    const float* be1 = (const float*)d_in[9];
    const float* g2 = (const float*)d_in[10];
    const float* be2 = (const float*)d_in[11];
    const float* Wc = (const float*)d_in[12];
    const float* bc = (const float*)d_in[13];
    const float* Wo = (const float*)d_in[14];
    const float* bo = (const float*)d_in[15];
    float* out = (float*)d_out;
    unsigned char* ws = (unsigned char*)d_ws;

    size_t off = 0;
    size_t o_xf = off;      off = al256(off + (size_t)NN * 64 * 4);
    size_t o_x16 = off;     off = al256(off + (size_t)NN * 64 * 2);
    size_t o_ef16 = off;    off = al256(off + (size_t)NE * 64 * 2);
    size_t o_WT = off;      off = al256(off + (size_t)128 * KPAD * 2);
    size_t o_nodesum = off; off = al256(off + (size_t)NN * 64 * 4);
    size_t o_estats = off;  off = al256(off + 256 * 4);
    size_t o_nstats = off;  off = al256(off + 128 * 4);
    size_t o_cnt1 = off;    off = al256(off + (size_t)NN * 4);
    size_t o_cnt3 = off;    off = al256(off + (size_t)NC * 4);
    size_t o_crsum = off;   off = al256(off + (size_t)NC * 64 * 4);
    size_t o_z = off;
    size_t need_z = o_z + (size_t)NE * 128 * 2;
    bool store_z = (ws_size >= need_z);

    float* xf = (float*)(ws + o_xf);
    f16* x16 = (f16*)(ws + o_x16);
    f16* ef16 = (f16*)(ws + o_ef16);
    f16* WT = (f16*)(ws + o_WT);
    float* nodesum = (float*)(ws + o_nodesum);
    float* estats = (float*)(ws + o_estats);
    float* nstats = (float*)(ws + o_nstats);
    float* cnt1 = (float*)(ws + o_cnt1);
    float* cnt3 = (float*)(ws + o_cnt3);
    float* crsum = (float*)(ws + o_crsum);
    f16* zbuf = (f16*)(ws + o_z);

    // zero nodesum..crsum (contiguous region)
    hipMemsetAsync(ws + o_nodesum, 0, o_crsum + (size_t)NC * 64 * 4 - o_nodesum, stream);

    k_prep_x<<<1024, 256, 0, stream>>>(node_fea, emb, xf, x16);
    k_prep_ef<<<4096, 256, 0, stream>>>(edge_fea, ef16);
    k_cnt<<<2048, 256, 0, stream>>>(idx1, idx3, cnt1, cnt3);

    for (int l = 0; l < 3; l++) {
        if (l > 0) {
            // re-zero nodesum + estats + nstats (contiguous)
            hipMemsetAsync(ws + o_nodesum, 0, o_cnt1 - o_nodesum, stream);
        }
        k_wt<<<96, 256, 0, stream>>>(Wf + (size_t)l * 169 * 128, WT);
        if (store_z) {
            k_edge_a<true><<<1024, 256, 0, stream>>>(x16, ef16, WT, idx1, idx2, estats, zbuf);
            k_edge_b<true><<<1024, 256, 0, stream>>>(x16, ef16, WT, idx1, idx2, estats, zbuf,
                                                     g1 + l * 128, be1 + l * 128, nodesum);
        } else {
            k_edge_a<false><<<1024, 256, 0, stream>>>(x16, ef16, WT, idx1, idx2, estats, zbuf);
            k_edge_b<false><<<1024, 256, 0, stream>>>(x16, ef16, WT, idx1, idx2, estats, zbuf,
                                                      g1 + l * 128, be1 + l * 128, nodesum);
        }
        k_node_stats<<<1024, 256, 0, stream>>>(nodesum, cnt1, nstats);
        k_node_apply<<<1024, 256, 0, stream>>>(nodesum, cnt1, nstats, g2 + l * 64,
                                               be2 + l * 64, xf, x16);
    }
    k_cry<<<1024, 256, 0, stream>>>(xf, idx3, crsum);
    k_out<<<2000, 128, 0, stream>>>(crsum, cnt3, Wc, bc, Wo, bo, out);
}